// Round 2
// baseline (341.341 us; speedup 1.0000x reference)
//
#include <hip/hip_runtime.h>

// YOLOv1 loss forward, MI355X — fused single-kernel, occupancy-optimized.
// preds/labels: (16384, 7, 7, 30) fp32, cell = 30 contiguous floats.
// R1 post-mortem: latency-bound at 18.8% occupancy (61KB LDS). R2: single
// 30.8KB LDS buffer used twice (preds then labels), all global loads issued
// up front (one HBM round trip), last-block-done fused final reduction.

#define NCELLS   802816                // 16384*7*7
#define CH       30
#define BLOCK    256
#define NBLOCKS  (NCELLS / BLOCK)      // 3136, exact
#define NVEC     (BLOCK * CH / 4)      // 1920 float4 per array per block
#define BATCH    16384.0

__device__ __forceinline__ float sq(float x) { return x * x; }

__device__ __forceinline__ float iou_f(float bx, float by, float bw, float bh,
                                       float lx, float ly, float lw, float lh) {
    float area1 = bw * bh;
    float area2 = lw * lh;
    float max_left  = fmaxf(bx - bw * 0.5f, lx - lw * 0.5f);
    float min_right = fminf(bx + bw * 0.5f, lx + lw * 0.5f);
    float max_top   = fmaxf(by - bh * 0.5f, ly - lh * 0.5f);
    float min_bot   = fminf(by + bh * 0.5f, ly + lh * 0.5f);
    float iw = min_right - max_left;
    float ih = min_bot - max_top;
    float inter = iw * ih;
    float iou = inter / (area1 + area2 - inter);
    return (iw > 0.f && ih > 0.f) ? iou : 0.f;
}

__global__ __launch_bounds__(BLOCK) void yolo_fused(
        const float* __restrict__ preds,
        const float* __restrict__ labels,
        float* __restrict__ partials,
        unsigned int* __restrict__ counter,
        float* __restrict__ out) {
    __shared__ alignas(16) float sbuf[BLOCK * CH];   // 30720 B, used twice
    __shared__ float warp_s[4];
    __shared__ int s_last;

    const int tid = threadIdx.x;
    const long base4 = (long)blockIdx.x * NVEC;
    const float4* p4 = reinterpret_cast<const float4*>(preds) + base4;
    const float4* l4 = reinterpret_cast<const float4*>(labels) + base4;
    float4* s4 = reinterpret_cast<float4*>(sbuf);

    // Issue ALL global loads up front (one HBM round trip; labels stay in
    // flight while preds are staged/consumed — compiler tracks vmcnt per reg).
    float4 pr[8], lr[8];
    bool g[8];
    #pragma unroll
    for (int i = 0; i < 8; ++i) g[i] = (i * BLOCK + tid) < NVEC;
    #pragma unroll
    for (int i = 0; i < 8; ++i) { if (g[i]) pr[i] = p4[i * BLOCK + tid]; }
    #pragma unroll
    for (int i = 0; i < 8; ++i) { if (g[i]) lr[i] = l4[i * BLOCK + tid]; }

    // Stage preds -> LDS -> registers.
    #pragma unroll
    for (int i = 0; i < 8; ++i) { if (g[i]) s4[i * BLOCK + tid] = pr[i]; }
    __syncthreads();
    float p[CH];
    {
        const float* P = sbuf + tid * CH;
        #pragma unroll
        for (int c = 0; c < CH; ++c) p[c] = P[c];
    }
    __syncthreads();

    // Reuse buffer for labels.
    #pragma unroll
    for (int i = 0; i < 8; ++i) { if (g[i]) s4[i * BLOCK + tid] = lr[i]; }
    __syncthreads();

    const float* L = sbuf + tid * CH;
    float l0 = L[0], l1 = L[1], l2 = L[2], l3 = L[3], lobj = L[4];

    float cls = 0.f;
    #pragma unroll
    for (int c = 10; c < CH; ++c) {
        float d = L[c] - p[c];
        cls += d * d;
    }

    float p0 = p[0], p1 = p[1], p2 = p[2], p3 = p[3], pc1 = p[4];
    float q0 = p[5], q1 = p[6], q2 = p[7], q3 = p[8], pc2 = p[9];

    const bool obj = (lobj == 1.0f);

    float iou1 = iou_f(p0, p1, p2, p3, l0, l1, l2, l3);
    float iou2 = iou_f(q0, q1, q2, q3, l0, l1, l2, l3);
    const bool sel1 = iou1 > iou2;

    float xy1 = sq(l0 - p0) + sq(l1 - p1);
    float xy2 = sq(l0 - q0) + sq(l1 - q1);

    float sl2 = sqrtf(l2), sl3 = sqrtf(l3);
    float wh1 = sq(sl2 - sqrtf(p2)) + sq(sl3 - sqrtf(p3));
    float wh2 = sq(sl2 - sqrtf(q2)) + sq(sl3 - sqrtf(q3));

    float o1 = sq(iou1 - pc1);
    float o2 = sq(iou2 - pc2);

    float n1 = pc2 * pc2;   // sel1 responsible -> penalize other box's conf
    float n2 = pc1 * pc1;

    float contrib;
    if (obj) {
        float xyt = sel1 ? xy1 : xy2;
        float wht = sel1 ? wh1 : wh2;
        float ot  = sel1 ? o1  : o2;
        float nt  = sel1 ? n1  : n2;
        contrib = 5.0f * xyt + wht + ot + 0.5f * nt + cls;
    } else {
        contrib = 0.5f * (pc1 * pc1 + pc2 * pc2);
    }

    // wave-64 reduction -> block partial
    float v = contrib;
    #pragma unroll
    for (int off = 32; off > 0; off >>= 1)
        v += __shfl_down(v, off, 64);
    if ((tid & 63) == 0) warp_s[tid >> 6] = v;
    __syncthreads();

    if (tid == 0) {
        float part = warp_s[0] + warp_s[1] + warp_s[2] + warp_s[3];
        __hip_atomic_store(&partials[blockIdx.x], part,
                           __ATOMIC_RELAXED, __HIP_MEMORY_SCOPE_AGENT);
        __threadfence();   // device-scope release of the partial
        unsigned int old = __hip_atomic_fetch_add(counter, 1u,
                           __ATOMIC_ACQ_REL, __HIP_MEMORY_SCOPE_AGENT);
        s_last = (old == NBLOCKS - 1);
    }
    __syncthreads();

    if (s_last) {
        __threadfence();   // acquire: all partials visible (device scope)
        double acc = 0.0;
        for (int i = tid; i < NBLOCKS; i += BLOCK)
            acc += (double)__hip_atomic_load(&partials[i],
                           __ATOMIC_RELAXED, __HIP_MEMORY_SCOPE_AGENT);
        double* sd = reinterpret_cast<double*>(sbuf);
        __syncthreads();   // sbuf no longer needed as labels
        sd[tid] = acc;
        __syncthreads();
        for (int off = BLOCK / 2; off > 0; off >>= 1) {
            if (tid < off) sd[tid] += sd[tid + off];
            __syncthreads();
        }
        if (tid == 0) out[0] = (float)(sd[0] / BATCH);
    }
}

extern "C" void kernel_launch(void* const* d_in, const int* in_sizes, int n_in,
                              void* d_out, int out_size, void* d_ws, size_t ws_size,
                              hipStream_t stream) {
    const float* preds  = (const float*)d_in[0];
    const float* labels = (const float*)d_in[1];
    float* out = (float*)d_out;

    unsigned int* counter = (unsigned int*)d_ws;             // 4 B
    float* partials = (float*)((char*)d_ws + 256);           // 12.5 KB

    hipMemsetAsync(counter, 0, sizeof(unsigned int), stream);
    yolo_fused<<<NBLOCKS, BLOCK, 0, stream>>>(preds, labels, partials, counter, out);
}

// Round 3
// 142.176 us; speedup vs baseline: 2.4008x; 2.4008x over previous
//
#include <hip/hip_runtime.h>

// YOLOv1 loss forward, MI355X.
// preds/labels: (16384, 7, 7, 30) fp32, cell = 30 contiguous floats.
// R1: two 30.7KB LDS buffers -> 2 blocks/CU, latency-bound, 42.5 us.
// R2: reg-array staging spilled to scratch (VGPR 44, WRITE_SIZE 188MB), 341 us.
// R3: single 30.7KB buffer staged twice with plain copy loop (no persistent
//     reg arrays -> no spill), 5 blocks/CU = 20 waves/CU, fused final reduction.

#define NCELLS   802816                // 16384*7*7
#define CH       30
#define BLOCK    256
#define NBLOCKS  (NCELLS / BLOCK)      // 3136, exact
#define NVEC     (BLOCK * CH / 4)      // 1920 float4 per array per block
#define BATCH    16384.0

__device__ __forceinline__ float sq(float x) { return x * x; }

__device__ __forceinline__ float iou_f(float bx, float by, float bw, float bh,
                                       float lx, float ly, float lw, float lh) {
    float area1 = bw * bh;
    float area2 = lw * lh;
    float max_left  = fmaxf(bx - bw * 0.5f, lx - lw * 0.5f);
    float min_right = fminf(bx + bw * 0.5f, lx + lw * 0.5f);
    float max_top   = fmaxf(by - bh * 0.5f, ly - lh * 0.5f);
    float min_bot   = fminf(by + bh * 0.5f, ly + lh * 0.5f);
    float iw = min_right - max_left;
    float ih = min_bot - max_top;
    float inter = iw * ih;
    float iou = inter / (area1 + area2 - inter);
    return (iw > 0.f && ih > 0.f) ? iou : 0.f;
}

__global__ __launch_bounds__(BLOCK) void yolo_fused(
        const float* __restrict__ preds,
        const float* __restrict__ labels,
        float* __restrict__ partials,
        unsigned int* __restrict__ counter,
        float* __restrict__ out) {
    __shared__ alignas(16) float sbuf[BLOCK * CH];   // 30720 B, staged twice
    __shared__ float warp_s[4];
    __shared__ int s_last;

    const int tid = threadIdx.x;
    const long base4 = (long)blockIdx.x * NVEC;
    const float4* p4 = reinterpret_cast<const float4*>(preds) + base4;
    const float4* l4 = reinterpret_cast<const float4*>(labels) + base4;
    float4* s4 = reinterpret_cast<float4*>(sbuf);

    // Stage preds -> LDS (coalesced float4, transient regs only).
    for (int i = tid; i < NVEC; i += BLOCK) s4[i] = p4[i];
    __syncthreads();

    // Pull this thread's cell of preds into registers.
    float p[CH];
    {
        const float* P = sbuf + tid * CH;
        #pragma unroll
        for (int c = 0; c < CH; ++c) p[c] = P[c];
    }
    __syncthreads();

    // Reuse the buffer for labels.
    for (int i = tid; i < NVEC; i += BLOCK) s4[i] = l4[i];
    __syncthreads();

    const float* L = sbuf + tid * CH;
    float l0 = L[0], l1 = L[1], l2 = L[2], l3 = L[3], lobj = L[4];

    float cls = 0.f;
    #pragma unroll
    for (int c = 10; c < CH; ++c) {
        float d = L[c] - p[c];
        cls += d * d;
    }

    float p0 = p[0], p1 = p[1], p2 = p[2], p3 = p[3], pc1 = p[4];
    float q0 = p[5], q1 = p[6], q2 = p[7], q3 = p[8], pc2 = p[9];

    const bool obj = (lobj == 1.0f);

    float iou1 = iou_f(p0, p1, p2, p3, l0, l1, l2, l3);
    float iou2 = iou_f(q0, q1, q2, q3, l0, l1, l2, l3);
    const bool sel1 = iou1 > iou2;

    float xy1 = sq(l0 - p0) + sq(l1 - p1);
    float xy2 = sq(l0 - q0) + sq(l1 - q1);

    float sl2 = sqrtf(l2), sl3 = sqrtf(l3);
    float wh1 = sq(sl2 - sqrtf(p2)) + sq(sl3 - sqrtf(p3));
    float wh2 = sq(sl2 - sqrtf(q2)) + sq(sl3 - sqrtf(q3));

    float o1 = sq(iou1 - pc1);
    float o2 = sq(iou2 - pc2);

    float n1 = pc2 * pc2;   // sel1 responsible -> penalize other box's conf
    float n2 = pc1 * pc1;

    float contrib;
    if (obj) {
        float xyt = sel1 ? xy1 : xy2;
        float wht = sel1 ? wh1 : wh2;
        float ot  = sel1 ? o1  : o2;
        float nt  = sel1 ? n1  : n2;
        contrib = 5.0f * xyt + wht + ot + 0.5f * nt + cls;
    } else {
        contrib = 0.5f * (pc1 * pc1 + pc2 * pc2);
    }

    // wave-64 reduction -> block partial
    float v = contrib;
    #pragma unroll
    for (int off = 32; off > 0; off >>= 1)
        v += __shfl_down(v, off, 64);
    if ((tid & 63) == 0) warp_s[tid >> 6] = v;
    __syncthreads();

    if (tid == 0) {
        float part = warp_s[0] + warp_s[1] + warp_s[2] + warp_s[3];
        __hip_atomic_store(&partials[blockIdx.x], part,
                           __ATOMIC_RELAXED, __HIP_MEMORY_SCOPE_AGENT);
        __threadfence();   // device-scope release of the partial
        unsigned int old = __hip_atomic_fetch_add(counter, 1u,
                           __ATOMIC_ACQ_REL, __HIP_MEMORY_SCOPE_AGENT);
        s_last = (old == NBLOCKS - 1);
    }
    __syncthreads();

    if (s_last) {
        __threadfence();   // acquire: all partials visible (device scope)
        double acc = 0.0;
        for (int i = tid; i < NBLOCKS; i += BLOCK)
            acc += (double)__hip_atomic_load(&partials[i],
                           __ATOMIC_RELAXED, __HIP_MEMORY_SCOPE_AGENT);
        double* sd = reinterpret_cast<double*>(sbuf);
        __syncthreads();   // all label reads are done (sync above)
        sd[tid] = acc;
        __syncthreads();
        for (int off = BLOCK / 2; off > 0; off >>= 1) {
            if (tid < off) sd[tid] += sd[tid + off];
            __syncthreads();
        }
        if (tid == 0) out[0] = (float)(sd[0] / BATCH);
    }
}

extern "C" void kernel_launch(void* const* d_in, const int* in_sizes, int n_in,
                              void* d_out, int out_size, void* d_ws, size_t ws_size,
                              hipStream_t stream) {
    const float* preds  = (const float*)d_in[0];
    const float* labels = (const float*)d_in[1];
    float* out = (float*)d_out;

    unsigned int* counter = (unsigned int*)d_ws;             // 4 B
    float* partials = (float*)((char*)d_ws + 256);           // 12.5 KB

    hipMemsetAsync(counter, 0, sizeof(unsigned int), stream);
    yolo_fused<<<NBLOCKS, BLOCK, 0, stream>>>(preds, labels, partials, counter, out);
}